// Round 4
// baseline (778.261 us; speedup 1.0000x reference)
//
#include <hip/hip_runtime.h>
#include <hip/hip_bf16.h>

typedef __attribute__((ext_vector_type(8))) __bf16 bf16x8;
typedef __attribute__((ext_vector_type(4))) __bf16 bf16x4;
typedef __attribute__((ext_vector_type(4))) float  f32x4;
typedef float f32x4u __attribute__((ext_vector_type(4), aligned(4)));

#define NB 16
#define NS 2048
#define ND 128
#define QT 64
#define KT 64
#define NKT (NS / KT)
#define SCALE 0.08838834764831845f  // 1/sqrt(128)

// ---------------- shared helpers ----------------
__device__ __forceinline__ bf16x8 ld8_256(const __bf16* base, int row, int byteInRow) {
    int off = row * 256 + (byteInRow ^ ((row & 7) << 4));
    return *reinterpret_cast<const bf16x8*>(reinterpret_cast<const char*>(base) + off);
}
__device__ __forceinline__ bf16x8 ld8_128(const __bf16* base, int row, int byteInRow) {
    int off = row * 128 + (byteInRow ^ ((row & 7) << 4));
    return *reinterpret_cast<const bf16x8*>(reinterpret_cast<const char*>(base) + off);
}

// ---------------- preconversion kernels ----------------
__global__ __launch_bounds__(256) void conv_qk(const float* __restrict__ q,
                                               const float* __restrict__ k,
                                               __bf16* __restrict__ qb,
                                               __bf16* __restrict__ kb) {
    size_t i = (size_t)blockIdx.x * 256 + threadIdx.x;
    const float4* qs = (const float4*)q;
    const float4* ks = (const float4*)k;
    float4 a = qs[2 * i], b = qs[2 * i + 1];
    bf16x8 o;
    o[0] = (__bf16)(a.x * SCALE); o[1] = (__bf16)(a.y * SCALE);
    o[2] = (__bf16)(a.z * SCALE); o[3] = (__bf16)(a.w * SCALE);
    o[4] = (__bf16)(b.x * SCALE); o[5] = (__bf16)(b.y * SCALE);
    o[6] = (__bf16)(b.z * SCALE); o[7] = (__bf16)(b.w * SCALE);
    *(bf16x8*)&qb[i * 8] = o;
    a = ks[2 * i]; b = ks[2 * i + 1];
    o[0] = (__bf16)a.x; o[1] = (__bf16)a.y; o[2] = (__bf16)a.z; o[3] = (__bf16)a.w;
    o[4] = (__bf16)b.x; o[5] = (__bf16)b.y; o[6] = (__bf16)b.z; o[7] = (__bf16)b.w;
    *(bf16x8*)&kb[i * 8] = o;
}

// v f32 [b][s][d] -> bf16 transposed [b][d][s], coalesced both sides via LDS
__global__ __launch_bounds__(256) void conv_vt(const float* __restrict__ v,
                                               __bf16* __restrict__ vt) {
    __shared__ __bf16 tile[128 * 128];   // 32 KB, d-index XOR-swizzled by (s&60)
    const int b = blockIdx.x >> 4, st = blockIdx.x & 15;
    const int s0 = st * 128, t = threadIdx.x;
    const int rlane = t >> 5, cv = (t & 31) * 4;
    #pragma unroll
    for (int it = 0; it < 16; ++it) {
        int s = rlane + it * 8;
        float4 f = *(const float4*)(v + ((size_t)b * NS + s0 + s) * ND + cv);
        bf16x4 h;
        h[0] = (__bf16)f.x; h[1] = (__bf16)f.y; h[2] = (__bf16)f.z; h[3] = (__bf16)f.w;
        *(bf16x4*)&tile[s * 128 + (cv ^ (s & 60))] = h;
    }
    __syncthreads();
    #pragma unroll
    for (int it = 0; it < 16; ++it) {
        int d = rlane + it * 8;
        bf16x4 o;
        #pragma unroll
        for (int e = 0; e < 4; ++e)
            o[e] = tile[(cv + e) * 128 + (d ^ ((cv + e) & 60))];
        *(bf16x4*)&vt[((size_t)b * ND + d) * NS + s0 + cv] = o;
    }
}

// ---------------- main fused kernel: barrier-free, all operands in regs ----------------
__global__ __launch_bounds__(256, 2) void qa_main(
    const __bf16* __restrict__ qb, const __bf16* __restrict__ kb,
    const __bf16* __restrict__ vtb, const int* __restrict__ mg,
    float* __restrict__ outg, float* __restrict__ pg)
{
    __shared__ unsigned short bmt[NKT * 256];               // 16 KB: per-thread mask bits
    __shared__ __align__(16) __bf16 Ps[4][16 * KT];         // 8 KB per-wave P staging

    const int bid = blockIdx.x;
    const int lb  = (bid & 7) * 64 + (bid >> 3);            // XCD swizzle (512 wgs)
    const int b   = lb >> 5;
    const int q0  = (lb & 31) * QT;
    const int t   = threadIdx.x;
    const int w   = t >> 6;
    const int l   = t & 63;
    const int l15 = l & 15;
    const int g   = l >> 4;
    const int myrow = w * 16 + l15;

    const __bf16* kbB  = kb  + (size_t)b * NS * ND;
    const __bf16* vtbB = vtb + (size_t)b * ND * NS;
    const int*    mrow = mg  + (size_t)(b * NS + q0 + myrow) * NS;

    if (t < QT) pg[(size_t)(b * NS + q0 + t) * (size_t)(NS + 1)] = 0.0f;  // sink col

    // Q fragments persistent in regs (B-operand)
    bf16x8 qf[4];
    {
        const __bf16* qrow = qb + (size_t)(b * NS + q0 + myrow) * ND;
        #pragma unroll
        for (int kc = 0; kc < 4; ++kc)
            qf[kc] = *(const bf16x8*)(qrow + kc * 32 + g * 8);
    }

    bf16x8 kf[16];                 // current K tile fragments (A-operand)
    f32x4  acc[4];

    auto loadK = [&](int k0) {
        #pragma unroll
        for (int c = 0; c < 4; ++c)
            #pragma unroll
            for (int kc = 0; kc < 4; ++kc)
                kf[c * 4 + kc] = *(const bf16x8*)(kbB + (size_t)(k0 + c * 16 + l15) * ND + kc * 32 + g * 8);
    };
    auto qk = [&]() {
        #pragma unroll
        for (int c = 0; c < 4; ++c) {
            f32x4 z = {0.f, 0.f, 0.f, 0.f}; acc[c] = z;
            #pragma unroll
            for (int kc = 0; kc < 4; ++kc)
                acc[c] = __builtin_amdgcn_mfma_f32_16x16x32_bf16(kf[c * 4 + kc], qf[kc], acc[c], 0, 0, 0);
        }
    };

    float mrun = -1e9f, srun = 0.0f;
    int4 mA[4], mB[4];

    auto stepA = [&](int kt, const int4* mcur, int4* mnxt) {
        qk();                                    // scores for tile kt (kf dead after)
        const int kn = kt + 1;
        if (kn < NKT) {                          // prefetch next K + next mask
            loadK(kn * KT);
            #pragma unroll
            for (int c = 0; c < 4; ++c)
                mnxt[c] = *(const int4*)(mrow + kn * KT + c * 16 + g * 4);
        }
        float sv[16]; unsigned bits = 0;
        #pragma unroll
        for (int c = 0; c < 4; ++c) {
            int mm[4] = {mcur[c].x, mcur[c].y, mcur[c].z, mcur[c].w};
            #pragma unroll
            for (int r = 0; r < 4; ++r) {
                bool on = mm[r] != 0;
                sv[c * 4 + r] = on ? acc[c][r] : -1e30f;
                bits |= on ? (1u << (c * 4 + r)) : 0u;
            }
        }
        float x0 = fmaxf(fmaxf(sv[0], sv[1]),  fmaxf(sv[2], sv[3]));
        float x1 = fmaxf(fmaxf(sv[4], sv[5]),  fmaxf(sv[6], sv[7]));
        float x2 = fmaxf(fmaxf(sv[8], sv[9]),  fmaxf(sv[10], sv[11]));
        float x3 = fmaxf(fmaxf(sv[12], sv[13]), fmaxf(sv[14], sv[15]));
        float mx = fmaxf(fmaxf(x0, x1), fmaxf(x2, x3));
        mx = fmaxf(mx, __shfl_xor(mx, 16));
        mx = fmaxf(mx, __shfl_xor(mx, 32));
        float mnew = fmaxf(mrun, mx);
        float e[16];
        #pragma unroll
        for (int i = 0; i < 16; ++i) e[i] = __expf(sv[i] - mnew);
        float s0 = (e[0] + e[1]) + (e[2] + e[3]);
        float s1 = (e[4] + e[5]) + (e[6] + e[7]);
        float s2 = (e[8] + e[9]) + (e[10] + e[11]);
        float s3 = (e[12] + e[13]) + (e[14] + e[15]);
        float ps = (s0 + s1) + (s2 + s3);
        ps += __shfl_xor(ps, 16);
        ps += __shfl_xor(ps, 32);
        srun = srun * __expf(mrun - mnew) + ps;
        mrun = mnew;
        bmt[kt * 256 + t] = (unsigned short)bits;
    };

    // ================= Sweep A: exact row max + sum (no barriers) =================
    loadK(0);
    #pragma unroll
    for (int c = 0; c < 4; ++c) mA[c] = *(const int4*)(mrow + c * 16 + g * 4);
    for (int kt = 0; kt < NKT; kt += 2) {
        stepA(kt,     mA, mB);
        stepA(kt + 1, mB, mA);
    }

    const float inv = 1.0f / (1.0f + srun);

    // ================= Sweep B: p write + PV (no barriers) =================
    f32x4 oacc[8];
    #pragma unroll
    for (int cf = 0; cf < 8; ++cf) { f32x4 z = {0.f, 0.f, 0.f, 0.f}; oacc[cf] = z; }

    bf16x8 vf[16];
    auto loadV = [&](int k0) {
        #pragma unroll
        for (int kc = 0; kc < 2; ++kc)
            #pragma unroll
            for (int cf = 0; cf < 8; ++cf)
                vf[kc * 8 + cf] = *(const bf16x8*)(vtbB + (size_t)(cf * 16 + l15) * NS + k0 + kc * 32 + g * 8);
    };

    loadK(0);
    loadV(0);
    const size_t prow = (size_t)(b * NS + q0 + myrow) * (size_t)(NS + 1);
    __bf16* Psw = Ps[w];

    for (int kt = 0; kt < NKT; ++kt) {
        const int k0 = kt * KT;
        qk();                                     // kf dead after
        if (kt + 1 < NKT) loadK(k0 + KT);         // prefetch next K (covered by p-phase+PV)

        unsigned bits = bmt[kt * 256 + t];
        #pragma unroll
        for (int c = 0; c < 4; ++c) {
            f32x4 pv; bf16x4 pb;
            #pragma unroll
            for (int r = 0; r < 4; ++r) {
                bool on = (bits >> (c * 4 + r)) & 1u;
                float p = on ? __expf(acc[c][r] - mrun) * inv : 0.0f;
                pv[r] = p; pb[r] = (__bf16)p;
            }
            *(f32x4u*)&pg[prow + 1 + k0 + c * 16 + g * 4] = pv;
            int off = l15 * 128 + ((c * 32 + g * 8) ^ ((l15 & 7) << 4));
            *(bf16x4*)((char*)Psw + off) = pb;
        }

        #pragma unroll
        for (int kc = 0; kc < 2; ++kc) {          // PV with V(kt) loaded last iter
            bf16x8 af = ld8_128(Psw, l15, kc * 64 + g * 16);
            #pragma unroll
            for (int cf = 0; cf < 8; ++cf)
                oacc[cf] = __builtin_amdgcn_mfma_f32_16x16x32_bf16(af, vf[kc * 8 + cf], oacc[cf], 0, 0, 0);
        }
        if (kt + 1 < NKT) loadV(k0 + KT);         // prefetch next V (covered by next QK+p)
    }

    #pragma unroll
    for (int cf = 0; cf < 8; ++cf)
        #pragma unroll
        for (int r = 0; r < 4; ++r)
            outg[(size_t)(b * NS + q0 + w * 16 + g * 4 + r) * ND + cf * 16 + l15] = oacc[cf][r];
}

// ---------------- fallback (ws too small): round-1 proven kernel ----------------
__device__ __forceinline__ void stage_rm(__bf16* dst, const float* src, int t) {
    int row = t >> 2, cg = t & 3;
    const float4* s4 = reinterpret_cast<const float4*>(src + (size_t)row * ND) + cg * 8;
    #pragma unroll
    for (int j = 0; j < 8; ++j) {
        float4 f = s4[j];
        bf16x4 h;
        h[0] = (__bf16)f.x; h[1] = (__bf16)f.y; h[2] = (__bf16)f.z; h[3] = (__bf16)f.w;
        int off = (cg * 64 + j * 8) ^ ((row & 7) << 4);
        *reinterpret_cast<bf16x4*>(reinterpret_cast<char*>(dst) + row * 256 + off) = h;
    }
}

__global__ __launch_bounds__(256, 2) void qa_fused_fb(
    const float* __restrict__ qg, const float* __restrict__ kg,
    const float* __restrict__ vg, const int* __restrict__ mg,
    float* __restrict__ outg, float* __restrict__ pg)
{
    __shared__ __bf16 Qs[QT * ND];
    __shared__ __bf16 Ks[KT * ND];
    __shared__ __bf16 Vt[ND * KT];
    __shared__ __bf16 Psf[4 * 16 * KT];
    __shared__ unsigned int bmf[QT][64];

    const int bid = blockIdx.x;
    const int lb  = (bid & 7) * 64 + (bid >> 3);
    const int b   = lb >> 5;
    const int q0  = (lb & 31) * QT;
    const int t   = threadIdx.x;
    const int w   = t >> 6;
    const int l   = t & 63;
    const int l15 = l & 15;
    const int g   = l >> 4;

    stage_rm(Qs, qg + ((size_t)b * NS + q0) * ND, t);
    if (t < QT) pg[((size_t)b * NS + q0 + t) * (size_t)(NS + 1)] = 0.0f;
    __syncthreads();

    bf16x8 qf[4];
    const int arow = w * 16 + l15;
    #pragma unroll
    for (int kc = 0; kc < 4; ++kc) qf[kc] = ld8_256(Qs, arow, kc * 64 + g * 16);

    float mrun[4], srun[4];
    #pragma unroll
    for (int r = 0; r < 4; ++r) { mrun[r] = -1e9f; srun[r] = 0.0f; }

    for (int kt = 0; kt < NKT; ++kt) {
        const int k0 = kt * KT;
        __syncthreads();
        stage_rm(Ks, kg + ((size_t)b * NS + k0) * ND, t);
        #pragma unroll 4
        for (int i = 0; i < 16; ++i) {
            int row = w * 16 + i;
            int mv = mg[((size_t)b * NS + (q0 + row)) * NS + k0 + l];
            unsigned long long bal = __ballot(mv != 0);
            if (l == 0) {
                bmf[row][2 * kt]     = (unsigned)bal;
                bmf[row][2 * kt + 1] = (unsigned)(bal >> 32);
            }
        }
        __syncthreads();

        f32x4 acc[4];
        #pragma unroll
        for (int c = 0; c < 4; ++c) {
            f32x4 z = {0.f, 0.f, 0.f, 0.f};
            acc[c] = z;
            #pragma unroll
            for (int kc = 0; kc < 4; ++kc) {
                bf16x8 bf = ld8_256(Ks, c * 16 + l15, kc * 64 + g * 16);
                acc[c] = __builtin_amdgcn_mfma_f32_16x16x32_bf16(qf[kc], bf, acc[c], 0, 0, 0);
            }
        }

        #pragma unroll
        for (int r = 0; r < 4; ++r) {
            const int row = w * 16 + g * 4 + r;
            const unsigned w0 = bmf[row][2 * kt], w1 = bmf[row][2 * kt + 1];
            float sv[4], tmax = -1e9f;
            #pragma unroll
            for (int c = 0; c < 4; ++c) {
                int cb = c * 16 + l15;
                unsigned word = (c < 2) ? w0 : w1;
                bool on = (word >> (cb & 31)) & 1u;
                float s = on ? acc[c][r] * SCALE : -1e9f;
                sv[c] = s;
                tmax = fmaxf(tmax, s);
            }
            #pragma unroll
            for (int d = 1; d < 16; d <<= 1) tmax = fmaxf(tmax, __shfl_xor(tmax, d));
            float mnew = fmaxf(mrun[r], tmax);
            float corr = __expf(mrun[r] - mnew);
            float ps = 0.f;
            #pragma unroll
            for (int c = 0; c < 4; ++c) ps += __expf(sv[c] - mnew);
            #pragma unroll
            for (int d = 1; d < 16; d <<= 1) ps += __shfl_xor(ps, d);
            srun[r] = srun[r] * corr + ps;
            mrun[r] = mnew;
        }
    }

    float inv[4];
    #pragma unroll
    for (int r = 0; r < 4; ++r) inv[r] = 1.0f / (1.0f + srun[r]);

    f32x4 oacc[8];
    #pragma unroll
    for (int cf = 0; cf < 8; ++cf) { f32x4 z = {0.f,0.f,0.f,0.f}; oacc[cf] = z; }

    __bf16* Psw = Psf + w * (16 * KT);

    for (int kt = 0; kt < NKT; ++kt) {
        const int k0 = kt * KT;
        __syncthreads();
        stage_rm(Ks, kg + ((size_t)b * NS + k0) * ND, t);
        {
            int kk = t >> 2, dg = t & 3;
            const float4* s4 = reinterpret_cast<const float4*>(vg + ((size_t)b * NS + k0 + kk) * ND) + dg * 8;
            #pragma unroll
            for (int j = 0; j < 8; ++j) {
                float4 f = s4[j];
                int d0 = dg * 32 + j * 4;
                float fv[4] = {f.x, f.y, f.z, f.w};
                #pragma unroll
                for (int e = 0; e < 4; ++e) {
                    int d = d0 + e;
                    int off = d * 128 + ((kk * 2) ^ ((d & 7) << 4));
                    *reinterpret_cast<__bf16*>(reinterpret_cast<char*>(Vt) + off) = (__bf16)fv[e];
                }
            }
        }
        __syncthreads();

        f32x4 acc[4];
        #pragma unroll
        for (int c = 0; c < 4; ++c) {
            f32x4 z = {0.f, 0.f, 0.f, 0.f};
            acc[c] = z;
            #pragma unroll
            for (int kc = 0; kc < 4; ++kc) {
                bf16x8 bf = ld8_256(Ks, c * 16 + l15, kc * 64 + g * 16);
                acc[c] = __builtin_amdgcn_mfma_f32_16x16x32_bf16(qf[kc], bf, acc[c], 0, 0, 0);
            }
        }

        #pragma unroll
        for (int r = 0; r < 4; ++r) {
            const int row16 = g * 4 + r;
            const int row = w * 16 + row16;
            const unsigned w0 = bmf[row][2 * kt], w1 = bmf[row][2 * kt + 1];
            const size_t prowf = ((size_t)b * NS + q0 + row) * (size_t)(NS + 1);
            #pragma unroll
            for (int c = 0; c < 4; ++c) {
                int cb = c * 16 + l15;
                unsigned word = (c < 2) ? w0 : w1;
                bool on = (word >> (cb & 31)) & 1u;
                float p = on ? __expf(acc[c][r] * SCALE - mrun[r]) * inv[r] : 0.0f;
                pg[prowf + 1 + k0 + cb] = p;
                int off = row16 * 128 + ((cb * 2) ^ ((row16 & 7) << 4));
                *reinterpret_cast<__bf16*>(reinterpret_cast<char*>(Psw) + off) = (__bf16)p;
            }
        }

        #pragma unroll
        for (int kc = 0; kc < 2; ++kc) {
            bf16x8 af = ld8_128(Psw, l15, kc * 64 + g * 16);
            #pragma unroll
            for (int cf = 0; cf < 8; ++cf) {
                bf16x8 vfr = ld8_128(Vt, cf * 16 + l15, kc * 64 + g * 16);
                oacc[cf] = __builtin_amdgcn_mfma_f32_16x16x32_bf16(af, vfr, oacc[cf], 0, 0, 0);
            }
        }
    }

    #pragma unroll
    for (int cf = 0; cf < 8; ++cf)
        #pragma unroll
        for (int r = 0; r < 4; ++r)
            outg[((size_t)b * NS + q0 + w * 16 + g * 4 + r) * ND + cf * 16 + l15] = oacc[cf][r];
}

extern "C" void kernel_launch(void* const* d_in, const int* in_sizes, int n_in,
                              void* d_out, int out_size, void* d_ws, size_t ws_size,
                              hipStream_t stream) {
    const float* q = (const float*)d_in[0];
    const float* k = (const float*)d_in[1];
    const float* v = (const float*)d_in[2];
    const int*  mk = (const int*)d_in[3];
    float* out = (float*)d_out;
    float* p   = out + (size_t)NB * NS * ND;

    const size_t elems = (size_t)NB * NS * ND;
    const size_t need  = elems * 2 * 3;

    if (ws_size >= need) {
        __bf16* qb = (__bf16*)d_ws;
        __bf16* kb = qb + elems;
        __bf16* vt = kb + elems;
        conv_qk<<<dim3((unsigned)(elems / 8 / 256)), dim3(256), 0, stream>>>(q, k, qb, kb);
        conv_vt<<<dim3(NB * 16), dim3(256), 0, stream>>>(v, vt);
        qa_main<<<dim3(NB * (NS / QT)), dim3(256), 0, stream>>>(qb, kb, vt, mk, out, p);
    } else {
        qa_fused_fb<<<dim3(NB * (NS / QT)), dim3(256), 0, stream>>>(q, k, v, mk, out, p);
    }
}

// Round 6
// 631.871 us; speedup vs baseline: 1.2317x; 1.2317x over previous
//
#include <hip/hip_runtime.h>
#include <hip/hip_bf16.h>

typedef __attribute__((ext_vector_type(8))) __bf16 bf16x8;
typedef __attribute__((ext_vector_type(4))) __bf16 bf16x4;
typedef __attribute__((ext_vector_type(4))) float  f32x4;
typedef float f32x4u __attribute__((ext_vector_type(4), aligned(4)));

#define NB 16
#define NS 2048
#define ND 128
#define QT 64
#define KT 64
#define NKT (NS / KT)
#define SCALE 0.08838834764831845f  // 1/sqrt(128)

#define VMW12() asm volatile("s_waitcnt vmcnt(12)" ::: "memory")
#define VMW8()  asm volatile("s_waitcnt vmcnt(8)"  ::: "memory")
#define VMW4()  asm volatile("s_waitcnt vmcnt(4)"  ::: "memory")
#define SCHED0() __builtin_amdgcn_sched_barrier(0)
#define SBAR()  __builtin_amdgcn_s_barrier()

// ---------------- shared helpers ----------------
__device__ __forceinline__ bf16x8 ld8_256(const __bf16* base, int row, int byteInRow) {
    int off = row * 256 + (byteInRow ^ ((row & 7) << 4));
    return *reinterpret_cast<const bf16x8*>(reinterpret_cast<const char*>(base) + off);
}
__device__ __forceinline__ bf16x8 ld8_128(const __bf16* base, int row, int byteInRow) {
    int off = row * 128 + (byteInRow ^ ((row & 7) << 4));
    return *reinterpret_cast<const bf16x8*>(reinterpret_cast<const char*>(base) + off);
}
__device__ __forceinline__ void glds16(const void* g, void* l) {
    __builtin_amdgcn_global_load_lds(
        (const __attribute__((address_space(1))) unsigned int*)g,
        (__attribute__((address_space(3))) unsigned int*)l, 16, 0, 0);
}

// ---------------- preconversion kernels ----------------
__global__ __launch_bounds__(256) void conv_qk(const float* __restrict__ q,
                                               const float* __restrict__ k,
                                               __bf16* __restrict__ qb,
                                               __bf16* __restrict__ kb) {
    size_t i = (size_t)blockIdx.x * 256 + threadIdx.x;
    const float4* qs = (const float4*)q;
    const float4* ks = (const float4*)k;
    float4 a = qs[2 * i], b = qs[2 * i + 1];
    bf16x8 o;
    o[0] = (__bf16)(a.x * SCALE); o[1] = (__bf16)(a.y * SCALE);
    o[2] = (__bf16)(a.z * SCALE); o[3] = (__bf16)(a.w * SCALE);
    o[4] = (__bf16)(b.x * SCALE); o[5] = (__bf16)(b.y * SCALE);
    o[6] = (__bf16)(b.z * SCALE); o[7] = (__bf16)(b.w * SCALE);
    *(bf16x8*)&qb[i * 8] = o;
    a = ks[2 * i]; b = ks[2 * i + 1];
    o[0] = (__bf16)a.x; o[1] = (__bf16)a.y; o[2] = (__bf16)a.z; o[3] = (__bf16)a.w;
    o[4] = (__bf16)b.x; o[5] = (__bf16)b.y; o[6] = (__bf16)b.z; o[7] = (__bf16)b.w;
    *(bf16x8*)&kb[i * 8] = o;
}

// v f32 [b][s][d] -> bf16 transposed [b][d][s], coalesced both sides via LDS
__global__ __launch_bounds__(256) void conv_vt(const float* __restrict__ v,
                                               __bf16* __restrict__ vt) {
    __shared__ __bf16 tile[128 * 128];
    const int b = blockIdx.x >> 4, st = blockIdx.x & 15;
    const int s0 = st * 128, t = threadIdx.x;
    const int rlane = t >> 5, cv = (t & 31) * 4;
    #pragma unroll
    for (int it = 0; it < 16; ++it) {
        int s = rlane + it * 8;
        float4 f = *(const float4*)(v + ((size_t)b * NS + s0 + s) * ND + cv);
        bf16x4 h;
        h[0] = (__bf16)f.x; h[1] = (__bf16)f.y; h[2] = (__bf16)f.z; h[3] = (__bf16)f.w;
        *(bf16x4*)&tile[s * 128 + (cv ^ (s & 60))] = h;
    }
    __syncthreads();
    #pragma unroll
    for (int it = 0; it < 16; ++it) {
        int d = rlane + it * 8;
        bf16x4 o;
        #pragma unroll
        for (int e = 0; e < 4; ++e)
            o[e] = tile[(cv + e) * 128 + (d ^ ((cv + e) & 60))];
        *(bf16x4*)&vt[((size_t)b * ND + d) * NS + s0 + cv] = o;
    }
}

// ---------------- main fused kernel: shared async staging + counted vmcnt ----------------
__global__ __launch_bounds__(256, 2) void qa_main(
    const __bf16* __restrict__ qb, const __bf16* __restrict__ kb,
    const __bf16* __restrict__ vtb, const int* __restrict__ mg,
    float* __restrict__ outg, float* __restrict__ pg)
{
    __shared__ __align__(16) char bufs[3][KT * ND * 2];     // 3 x 16 KB K/V tiles
    __shared__ unsigned short bmt[NKT * 256];               // 16 KB per-thread mask bits
    __shared__ __align__(16) __bf16 Ps[4][16 * KT];         // 8 KB per-wave P staging

    const int bid = blockIdx.x;
    const int lb  = (bid & 7) * 64 + (bid >> 3);            // XCD swizzle (512 wgs)
    const int b   = lb >> 5;
    const int q0  = (lb & 31) * QT;
    const int t   = threadIdx.x;
    const int w   = t >> 6;
    const int l15 = t & 15;
    const int g   = (t & 63) >> 4;
    const int myrow = w * 16 + l15;

    const __bf16* kbB  = kb  + (size_t)b * NS * ND;
    const __bf16* vtbB = vtb + (size_t)b * ND * NS;
    const int*    mrow = mg  + (size_t)(b * NS + q0 + myrow) * NS;

    // sink column (oldest vmem op; retired by the first counted wait)
    if (t < QT) pg[(size_t)(b * NS + q0 + t) * (size_t)(NS + 1)] = 0.0f;

    // Q fragments persistent in regs (B-operand)
    bf16x8 qf[4];
    {
        const __bf16* qrow = qb + (size_t)(b * NS + q0 + myrow) * ND;
        #pragma unroll
        for (int kc = 0; kc < 4; ++kc)
            qf[kc] = *(const bf16x8*)(qrow + kc * 32 + g * 8);
    }

    auto stageK = [&](char* buf, int k0) {
        #pragma unroll
        for (int i = 0; i < 4; ++i) {
            int c = i * 256 + t;
            int row = c >> 4, pc = c & 15, lc = pc ^ (row & 7);
            glds16(kbB + (size_t)(k0 + row) * ND + lc * 8, buf + c * 16);
        }
    };
    auto stageV = [&](char* buf, int k0) {
        #pragma unroll
        for (int i = 0; i < 4; ++i) {
            int c = i * 256 + t;
            int d = c >> 3, pc = c & 7, lc = pc ^ (d & 7);
            glds16(vtbB + (size_t)d * NS + k0 + lc * 8, buf + c * 16);
        }
    };

    float mrun = -1e9f, srun = 0.0f;
    int4 mA[4], mB[4];

    // ================= Sweep A: exact row max + sum =================
    // 3-buffer K rotation, one barrier/tile, counted vmcnt (never 0)
    stageK(bufs[0], 0);
    stageK(bufs[1], KT);
    #pragma unroll
    for (int c = 0; c < 4; ++c) mA[c] = *(const int4*)(mrow + c * 16 + g * 4);
    VMW8();                      // K(0) resident (stage1 + mask0 outstanding)
    SCHED0(); SBAR(); SCHED0();

    auto stepA = [&](int kt, const int4* mcur, int4* mnxt) {
        if (kt + 2 < NKT) stageK(bufs[(kt + 2) % 3], (kt + 2) * KT);
        if (kt + 1 < NKT) {
            #pragma unroll
            for (int c = 0; c < 4; ++c)
                mnxt[c] = *(const int4*)(mrow + (kt + 1) * KT + c * 16 + g * 4);
        }
        const __bf16* Kbuf = (const __bf16*)bufs[kt % 3];
        f32x4 acc[4];
        #pragma unroll
        for (int c = 0; c < 4; ++c) {
            f32x4 z = {0.f, 0.f, 0.f, 0.f}; acc[c] = z;
            #pragma unroll
            for (int kc = 0; kc < 4; ++kc) {
                bf16x8 kf = ld8_256(Kbuf, c * 16 + l15, kc * 64 + g * 16);
                acc[c] = __builtin_amdgcn_mfma_f32_16x16x32_bf16(kf, qf[kc], acc[c], 0, 0, 0);
            }
        }
        float sv[16]; unsigned bits = 0;
        #pragma unroll
        for (int c = 0; c < 4; ++c) {
            int mm[4] = {mcur[c].x, mcur[c].y, mcur[c].z, mcur[c].w};
            #pragma unroll
            for (int r = 0; r < 4; ++r) {
                bool on = mm[r] != 0;
                sv[c * 4 + r] = on ? acc[c][r] : -1e30f;
                bits |= on ? (1u << (c * 4 + r)) : 0u;
            }
        }
        float x0 = fmaxf(fmaxf(sv[0], sv[1]),  fmaxf(sv[2], sv[3]));
        float x1 = fmaxf(fmaxf(sv[4], sv[5]),  fmaxf(sv[6], sv[7]));
        float x2 = fmaxf(fmaxf(sv[8], sv[9]),  fmaxf(sv[10], sv[11]));
        float x3 = fmaxf(fmaxf(sv[12], sv[13]), fmaxf(sv[14], sv[15]));
        float mx = fmaxf(fmaxf(x0, x1), fmaxf(x2, x3));
        mx = fmaxf(mx, __shfl_xor(mx, 16));
        mx = fmaxf(mx, __shfl_xor(mx, 32));
        float mnew = fmaxf(mrun, mx);
        float e[16];
        #pragma unroll
        for (int i = 0; i < 16; ++i) e[i] = __expf(sv[i] - mnew);
        float p0 = (e[0] + e[1]) + (e[2] + e[3]);
        float p1 = (e[4] + e[5]) + (e[6] + e[7]);
        float p2 = (e[8] + e[9]) + (e[10] + e[11]);
        float p3 = (e[12] + e[13]) + (e[14] + e[15]);
        float ps = (p0 + p1) + (p2 + p3);
        ps += __shfl_xor(ps, 16);
        ps += __shfl_xor(ps, 32);
        srun = srun * __expf(mrun - mnew) + ps;
        mrun = mnew;
        bmt[kt * 256 + t] = (unsigned short)bits;
        // ensure K(kt+1) resident before next tile; prefetches stay in flight
        if (kt <= NKT - 3)      { VMW12(); }
        else if (kt == NKT - 2) { VMW8();  }
        SCHED0(); SBAR(); SCHED0();
    };

    for (int kt = 0; kt < NKT; kt += 2) {
        stepA(kt,     mA, mB);
        stepA(kt + 1, mB, mA);
    }

    const float inv = 1.0f / (1.0f + srun);

    // ================= Sweep B: p write + PV =================
    f32x4 oacc[8];
    #pragma unroll
    for (int cf = 0; cf < 8; ++cf) { f32x4 z = {0.f, 0.f, 0.f, 0.f}; oacc[cf] = z; }

    int iA = 0, iB = 1, iC = 2;
    stageK(bufs[0], 0);
    stageV(bufs[1], 0);
    VMW4();                      // K(0) resident (V(0) still in flight)
    SCHED0(); SBAR(); SCHED0();

    const size_t prow = (size_t)(b * NS + q0 + myrow) * (size_t)(NS + 1);
    __bf16* Psw = Ps[w];

    for (int kt = 0; kt < NKT; ++kt) {
        const int k0 = kt * KT;
        if (kt + 1 < NKT) stageK(bufs[iC], k0 + KT);

        const __bf16* Kbuf = (const __bf16*)bufs[iA];
        f32x4 acc[4];
        #pragma unroll
        for (int c = 0; c < 4; ++c) {
            f32x4 z = {0.f, 0.f, 0.f, 0.f}; acc[c] = z;
            #pragma unroll
            for (int kc = 0; kc < 4; ++kc) {
                bf16x8 kf = ld8_256(Kbuf, c * 16 + l15, kc * 64 + g * 16);
                acc[c] = __builtin_amdgcn_mfma_f32_16x16x32_bf16(kf, qf[kc], acc[c], 0, 0, 0);
            }
        }

        unsigned bits = bmt[kt * 256 + t];
        #pragma unroll
        for (int c = 0; c < 4; ++c) {
            f32x4 pv; bf16x4 pb;
            #pragma unroll
            for (int r = 0; r < 4; ++r) {
                bool on = (bits >> (c * 4 + r)) & 1u;
                float p = on ? __expf(acc[c][r] - mrun) * inv : 0.0f;
                pv[r] = p; pb[r] = (__bf16)p;
            }
            *(f32x4u*)&pg[prow + 1 + k0 + c * 16 + g * 4] = pv;
            int off = l15 * 128 + ((c * 32 + g * 8) ^ ((l15 & 7) << 4));
            *(bf16x4*)((char*)Psw + off) = pb;
        }

        // V(kt) resident; other waves done reading K buffer iA
        if (kt < NKT - 1) { VMW8(); } else { VMW4(); }
        SCHED0(); SBAR(); SCHED0();

        if (kt + 1 < NKT) stageV(bufs[iA], k0 + KT);

        const __bf16* Vbuf = (const __bf16*)bufs[iB];
        #pragma unroll
        for (int kc = 0; kc < 2; ++kc) {
            bf16x8 af = ld8_128(Psw, l15, kc * 64 + g * 16);
            #pragma unroll
            for (int cf = 0; cf < 8; ++cf) {
                bf16x8 vf = ld8_128(Vbuf, cf * 16 + l15, kc * 64 + g * 16);
                oacc[cf] = __builtin_amdgcn_mfma_f32_16x16x32_bf16(af, vf, oacc[cf], 0, 0, 0);
            }
        }

        // K(kt+1) resident before next tile reads it; V buffer iB fully read
        if (kt < NKT - 1) { VMW8(); }
        SCHED0(); SBAR(); SCHED0();

        int nA = iC, nB = iA, nC = iB;
        iA = nA; iB = nB; iC = nC;
    }

    #pragma unroll
    for (int cf = 0; cf < 8; ++cf)
        #pragma unroll
        for (int r = 0; r < 4; ++r)
            outg[(size_t)(b * NS + q0 + w * 16 + g * 4 + r) * ND + cf * 16 + l15] = oacc[cf][r];
}

// ---------------- fallback (ws too small): round-1 proven kernel ----------------
__device__ __forceinline__ void stage_rm(__bf16* dst, const float* src, int t) {
    int row = t >> 2, cg = t & 3;
    const float4* s4 = reinterpret_cast<const float4*>(src + (size_t)row * ND) + cg * 8;
    #pragma unroll
    for (int j = 0; j < 8; ++j) {
        float4 f = s4[j];
        bf16x4 h;
        h[0] = (__bf16)f.x; h[1] = (__bf16)f.y; h[2] = (__bf16)f.z; h[3] = (__bf16)f.w;
        int off = (cg * 64 + j * 8) ^ ((row & 7) << 4);
        *reinterpret_cast<bf16x4*>(reinterpret_cast<char*>(dst) + row * 256 + off) = h;
    }
}

__global__ __launch_bounds__(256, 2) void qa_fused_fb(
    const float* __restrict__ qg, const float* __restrict__ kg,
    const float* __restrict__ vg, const int* __restrict__ mg,
    float* __restrict__ outg, float* __restrict__ pg)
{
    __shared__ __bf16 Qs[QT * ND];
    __shared__ __bf16 Ks[KT * ND];
    __shared__ __bf16 Vt[ND * KT];
    __shared__ __bf16 Psf[4 * 16 * KT];
    __shared__ unsigned int bmf[QT][64];

    const int bid = blockIdx.x;
    const int lb  = (bid & 7) * 64 + (bid >> 3);
    const int b   = lb >> 5;
    const int q0  = (lb & 31) * QT;
    const int t   = threadIdx.x;
    const int w   = t >> 6;
    const int l   = t & 63;
    const int l15 = l & 15;
    const int g   = l >> 4;

    stage_rm(Qs, qg + ((size_t)b * NS + q0) * ND, t);
    if (t < QT) pg[((size_t)b * NS + q0 + t) * (size_t)(NS + 1)] = 0.0f;
    __syncthreads();

    bf16x8 qf[4];
    const int arow = w * 16 + l15;
    #pragma unroll
    for (int kc = 0; kc < 4; ++kc) qf[kc] = ld8_256(Qs, arow, kc * 64 + g * 16);

    float mrun[4], srun[4];
    #pragma unroll
    for (int r = 0; r < 4; ++r) { mrun[r] = -1e9f; srun[r] = 0.0f; }

    for (int kt = 0; kt < NKT; ++kt) {
        const int k0 = kt * KT;
        __syncthreads();
        stage_rm(Ks, kg + ((size_t)b * NS + k0) * ND, t);
        #pragma unroll 4
        for (int i = 0; i < 16; ++i) {
            int row = w * 16 + i;
            int mv = mg[((size_t)b * NS + (q0 + row)) * NS + k0 + l];
            unsigned long long bal = __ballot(mv != 0);
            if (l == 0) {
                bmf[row][2 * kt]     = (unsigned)bal;
                bmf[row][2 * kt + 1] = (unsigned)(bal >> 32);
            }
        }
        __syncthreads();

        f32x4 acc[4];
        #pragma unroll
        for (int c = 0; c < 4; ++c) {
            f32x4 z = {0.f, 0.f, 0.f, 0.f};
            acc[c] = z;
            #pragma unroll
            for (int kc = 0; kc < 4; ++kc) {
                bf16x8 bf = ld8_256(Ks, c * 16 + l15, kc * 64 + g * 16);
                acc[c] = __builtin_amdgcn_mfma_f32_16x16x32_bf16(qf[kc], bf, acc[c], 0, 0, 0);
            }
        }

        #pragma unroll
        for (int r = 0; r < 4; ++r) {
            const int row = w * 16 + g * 4 + r;
            const unsigned w0 = bmf[row][2 * kt], w1 = bmf[row][2 * kt + 1];
            float sv[4], tmax = -1e9f;
            #pragma unroll
            for (int c = 0; c < 4; ++c) {
                int cb = c * 16 + l15;
                unsigned word = (c < 2) ? w0 : w1;
                bool on = (word >> (cb & 31)) & 1u;
                float s = on ? acc[c][r] * SCALE : -1e9f;
                sv[c] = s;
                tmax = fmaxf(tmax, s);
            }
            #pragma unroll
            for (int d = 1; d < 16; d <<= 1) tmax = fmaxf(tmax, __shfl_xor(tmax, d));
            float mnew = fmaxf(mrun[r], tmax);
            float corr = __expf(mrun[r] - mnew);
            float ps = 0.f;
            #pragma unroll
            for (int c = 0; c < 4; ++c) ps += __expf(sv[c] - mnew);
            #pragma unroll
            for (int d = 1; d < 16; d <<= 1) ps += __shfl_xor(ps, d);
            srun[r] = srun[r] * corr + ps;
            mrun[r] = mnew;
        }
    }

    float inv[4];
    #pragma unroll
    for (int r = 0; r < 4; ++r) inv[r] = 1.0f / (1.0f + srun[r]);

    f32x4 oacc[8];
    #pragma unroll
    for (int cf = 0; cf < 8; ++cf) { f32x4 z = {0.f,0.f,0.f,0.f}; oacc[cf] = z; }

    __bf16* Psw = Psf + w * (16 * KT);

    for (int kt = 0; kt < NKT; ++kt) {
        const int k0 = kt * KT;
        __syncthreads();
        stage_rm(Ks, kg + ((size_t)b * NS + k0) * ND, t);
        {
            int kk = t >> 2, dg = t & 3;
            const float4* s4 = reinterpret_cast<const float4*>(vg + ((size_t)b * NS + k0 + kk) * ND) + dg * 8;
            #pragma unroll
            for (int j = 0; j < 8; ++j) {
                float4 f = s4[j];
                int d0 = dg * 32 + j * 4;
                float fv[4] = {f.x, f.y, f.z, f.w};
                #pragma unroll
                for (int e = 0; e < 4; ++e) {
                    int d = d0 + e;
                    int off = d * 128 + ((kk * 2) ^ ((d & 7) << 4));
                    *reinterpret_cast<__bf16*>(reinterpret_cast<char*>(Vt) + off) = (__bf16)fv[e];
                }
            }
        }
        __syncthreads();

        f32x4 acc[4];
        #pragma unroll
        for (int c = 0; c < 4; ++c) {
            f32x4 z = {0.f, 0.f, 0.f, 0.f};
            acc[c] = z;
            #pragma unroll
            for (int kc = 0; kc < 4; ++kc) {
                bf16x8 bf = ld8_256(Ks, c * 16 + l15, kc * 64 + g * 16);
                acc[c] = __builtin_amdgcn_mfma_f32_16x16x32_bf16(qf[kc], bf, acc[c], 0, 0, 0);
            }
        }

        #pragma unroll
        for (int r = 0; r < 4; ++r) {
            const int row16 = g * 4 + r;
            const int row = w * 16 + row16;
            const unsigned w0 = bmf[row][2 * kt], w1 = bmf[row][2 * kt + 1];
            const size_t prowf = ((size_t)b * NS + q0 + row) * (size_t)(NS + 1);
            #pragma unroll
            for (int c = 0; c < 4; ++c) {
                int cb = c * 16 + l15;
                unsigned word = (c < 2) ? w0 : w1;
                bool on = (word >> (cb & 31)) & 1u;
                float p = on ? __expf(acc[c][r] * SCALE - mrun[r]) * inv[r] : 0.0f;
                pg[prowf + 1 + k0 + cb] = p;
                int off = row16 * 128 + ((cb * 2) ^ ((row16 & 7) << 4));
                *reinterpret_cast<__bf16*>(reinterpret_cast<char*>(Psw) + off) = (__bf16)p;
            }
        }

        #pragma unroll
        for (int kc = 0; kc < 2; ++kc) {
            bf16x8 af = ld8_128(Psw, l15, kc * 64 + g * 16);
            #pragma unroll
            for (int cf = 0; cf < 8; ++cf) {
                bf16x8 vfr = ld8_128(Vt, cf * 16 + l15, kc * 64 + g * 16);
                oacc[cf] = __builtin_amdgcn_mfma_f32_16x16x32_bf16(af, vfr, oacc[cf], 0, 0, 0);
            }
        }
    }

    #pragma unroll
    for (int cf = 0; cf < 8; ++cf)
        #pragma unroll
        for (int r = 0; r < 4; ++r)
            outg[((size_t)b * NS + q0 + w * 16 + g * 4 + r) * ND + cf * 16 + l15] = oacc[cf][r];
}

extern "C" void kernel_launch(void* const* d_in, const int* in_sizes, int n_in,
                              void* d_out, int out_size, void* d_ws, size_t ws_size,
                              hipStream_t stream) {
    const float* q = (const float*)d_in[0];
    const float* k = (const float*)d_in[1];
    const float* v = (const float*)d_in[2];
    const int*  mk = (const int*)d_in[3];
    float* out = (float*)d_out;
    float* p   = out + (size_t)NB * NS * ND;

    const size_t elems = (size_t)NB * NS * ND;
    const size_t need  = elems * 2 * 3;

    if (ws_size >= need) {
        __bf16* qb = (__bf16*)d_ws;
        __bf16* kb = qb + elems;
        __bf16* vt = kb + elems;
        conv_qk<<<dim3((unsigned)(elems / 8 / 256)), dim3(256), 0, stream>>>(q, k, qb, kb);
        conv_vt<<<dim3(NB * 16), dim3(256), 0, stream>>>(v, vt);
        qa_main<<<dim3(NB * (NS / QT)), dim3(256), 0, stream>>>(qb, kb, vt, mk, out, p);
    } else {
        qa_fused_fb<<<dim3(NB * (NS / QT)), dim3(256), 0, stream>>>(q, k, v, mk, out, p);
    }
}